// Round 22
// baseline (93.628 us; speedup 1.0000x reference)
//
#include <hip/hip_runtime.h>
#include <hip/hip_bf16.h>
#include <cstddef>
#include <cstdint>

// Problem constants (fixed by the reference setup)
#define N_B   8
#define L_L   4096
#define S_S   4096
#define H_H   8
#define D_D   64
#define NH    64          // N_B * H_H
// KV_aug layout (d-major): rows 0..63 = KV[d][v] (stride 68, cols 64..67 pad),
// row 64 = K_sum[d] (indexed by d in cols 0..63). KVSZ floats per (n,h).
#define KVLD  68
#define KVSZ  (65 * KVLD)   // 4420
#define ROWF  (H_H * D_D)   // 512 floats per s-row
#define LDSH  256           // shorts per d-row of the staged chunk (s = 0..255)

typedef float f32x4 __attribute__((ext_vector_type(4)));
typedef short bf16x8 __attribute__((ext_vector_type(8)));
typedef unsigned int uint32x4 __attribute__((ext_vector_type(4)));

__device__ __forceinline__ float elu1(float x) {
    // elu(x)+1 : x>0 ? x+1 : exp(x)
    return x > 0.f ? x + 1.f : __expf(x);
}

__device__ __forceinline__ unsigned int pkbf(float a, float b) {
    __hip_bfloat162 t = __float22bfloat162_rn(make_float2(a, b));
    return *reinterpret_cast<unsigned int*>(&t);
}

// ---------------------------------------------------------------------------
// Phase 1 (v17): stage-once bf16 MFMA (the phase-2 recipe).
//  v15/v16 ledger: per-tile convoy {issue -> tiny compute -> vmcnt(0) ->
//  barrier} pays ~full memory latency per tile; BOTH wave-private and
//  coalesced variants pin at ~60us regardless of occupancy/coalescing
//  (warm replays: 290GB/s, same dur -> latency-structure-bound, not BW).
//  Phase 2 (same grid, 2 blocks/CU, stage-once + 1 barrier) runs 20us.
//  v17: stage the WHOLE 256-s chunk once: per thread 32 independent float4
//  loads (2 slots x {8 K + 8 V}, 256B-coalesced per 16-thread group),
//  register 8x4 transpose, pack bf16x8, b128 LDS writes with granule swizzle
//  s_block ^= (d&7) (8-way = b128 optimum on write AND fragment read).
//  One barrier -> 8 ksteps x 5 MFMA/wave (v16's verified d-slab split, m89
//  C-layout, ones-column ksum) -> barrier -> v16 epilogue. LDS 64KB union'd
//  with acc -> 2 blocks/CU (phase2's proven residency).
// ---------------------------------------------------------------------------
__global__ __launch_bounds__(256, 2)
void la_phase1(const float* __restrict__ Kin, const float* __restrict__ Vin,
               float* __restrict__ partials, int split, int schunk)
{
    __shared__ union {
        struct { short Kt[64 * LDSH]; short Vt[64 * LDSH]; } st;  // 64 KB
        float acc[64 * 68];                                       // 17.4 KB
    } sm;

    const int b     = blockIdx.x;
    const int nh    = b / split;
    const int chunk = b - nh * split;
    const int n     = nh >> 3;
    const int h     = nh & 7;
    const int s0    = chunk * schunk;   // schunk == 256

    const int tid  = threadIdx.x;
    const int w    = tid >> 6;
    const int lane = tid & 63;
    const int a2   = lane & 15;        // MFMA fragment lane index
    const int kg   = lane >> 4;        // k-group (0..3)

    const size_t base = (size_t)n * S_S * ROWF + h * D_D;

    // ---- stage: 2 slots/thread; slot covers rows rg*8..rg*8+7, d c4i*4..+3 ----
    #pragma unroll
    for (int outer = 0; outer < 2; ++outer) {
        const int slot = outer * 256 + tid;
        const int rg   = slot >> 4;          // 0..31 (s-block of 8 rows)
        const int c4i  = slot & 15;          // 16B column group
        const float* kp = Kin + base + (size_t)(s0 + rg * 8) * ROWF + c4i * 4;
        const float* vp = Vin + base + (size_t)(s0 + rg * 8) * ROWF + c4i * 4;

        f32x4 kj[8], vj[8];
        #pragma unroll
        for (int j = 0; j < 8; ++j) kj[j] = *(const f32x4*)(kp + (size_t)j * ROWF);
        #pragma unroll
        for (int j = 0; j < 8; ++j) vj[j] = *(const f32x4*)(vp + (size_t)j * ROWF);

        #pragma unroll
        for (int i = 0; i < 4; ++i) {
            const int d    = c4i * 4 + i;
            const int gblk = rg ^ (d & 7);   // granule XOR swizzle
            uint32x4 pk, pv;
            pk.x = pkbf(elu1(kj[0][i]), elu1(kj[1][i]));
            pk.y = pkbf(elu1(kj[2][i]), elu1(kj[3][i]));
            pk.z = pkbf(elu1(kj[4][i]), elu1(kj[5][i]));
            pk.w = pkbf(elu1(kj[6][i]), elu1(kj[7][i]));
            pv.x = pkbf(vj[0][i], vj[1][i]);
            pv.y = pkbf(vj[2][i], vj[3][i]);
            pv.z = pkbf(vj[4][i], vj[5][i]);
            pv.w = pkbf(vj[6][i], vj[7][i]);
            *(uint32x4*)&sm.st.Kt[d * LDSH + (gblk << 3)] = pk;
            *(uint32x4*)&sm.st.Vt[d * LDSH + (gblk << 3)] = pv;
        }
    }
    __syncthreads();

    // ---- compute: wave w owns d-slab w*16..w*16+15; 8 ksteps x 5 MFMA ----
    f32x4 acc[4];
    f32x4 acck;
    const f32x4 z4 = {0.f, 0.f, 0.f, 0.f};
    acck = z4;
    #pragma unroll
    for (int nn = 0; nn < 4; ++nn) acc[nn] = z4;
    const bf16x8 ones = {0x3F80, 0x3F80, 0x3F80, 0x3F80,
                         0x3F80, 0x3F80, 0x3F80, 0x3F80};   // bf16 1.0 x8

    const int swz = a2 & 7;   // d&7 for all rows nn*16+a2 and w*16+a2
    #pragma unroll
    for (int ks = 0; ks < 8; ++ks) {
        const int goff = (((ks << 2) | kg) ^ swz) << 3;   // swizzled granule
        const bf16x8 af = *(const bf16x8*)&sm.st.Kt[(w * 16 + a2) * LDSH + goff];
        const bf16x8 b0 = *(const bf16x8*)&sm.st.Vt[( 0 + a2) * LDSH + goff];
        const bf16x8 b1 = *(const bf16x8*)&sm.st.Vt[(16 + a2) * LDSH + goff];
        const bf16x8 b2 = *(const bf16x8*)&sm.st.Vt[(32 + a2) * LDSH + goff];
        const bf16x8 b3 = *(const bf16x8*)&sm.st.Vt[(48 + a2) * LDSH + goff];
        acc[0] = __builtin_amdgcn_mfma_f32_16x16x32_bf16(af, b0, acc[0], 0, 0, 0);
        acc[1] = __builtin_amdgcn_mfma_f32_16x16x32_bf16(af, b1, acc[1], 0, 0, 0);
        acc[2] = __builtin_amdgcn_mfma_f32_16x16x32_bf16(af, b2, acc[2], 0, 0, 0);
        acc[3] = __builtin_amdgcn_mfma_f32_16x16x32_bf16(af, b3, acc[3], 0, 0, 0);
        acck   = __builtin_amdgcn_mfma_f32_16x16x32_bf16(af, ones, acck, 0, 0, 0);
    }
    __syncthreads();   // all waves done reading Kt/Vt; acc (union) safe

    // ---- epilogue: slabs disjoint -> direct writes into sm.acc ----
    // C layout (m89): col = a2 -> v = nn*16+a2; row = kg*4+r -> d = w*16+kg*4+r
    #pragma unroll
    for (int nn = 0; nn < 4; ++nn)
        #pragma unroll
        for (int r = 0; r < 4; ++r)
            sm.acc[(w * 16 + kg * 4 + r) * 68 + nn * 16 + a2] = acc[nn][r];
    if (a2 == 0) {
        #pragma unroll
        for (int r = 0; r < 4; ++r)
            sm.acc[(w * 16 + kg * 4 + r) * 68 + 64] = acck[r];
    }
    __syncthreads();

    // write this block's partial KV_aug[65][68] d-major (row 64 = K_sum, pads 0)
    float* outp = partials + (size_t)b * KVSZ;
    for (int idx = tid; idx < KVSZ; idx += 256) {
        const int r = idx / KVLD;
        const int c = idx - r * KVLD;
        float val = 0.f;
        if (c < 64) {
            if (r < 64)
                val = sm.acc[idx];          // [d][v] stride 68 == same layout
            else
                val = sm.acc[c * 68 + 64];  // ksum for d=c (pad col 64)
        }
        outp[idx] = val;
    }
}

// ---------------------------------------------------------------------------
// Reduce: sum the `split` partials per (n,h) -> kvt[nh][65][68]
// ---------------------------------------------------------------------------
__global__ __launch_bounds__(256)
void la_reduce(const float* __restrict__ partials, float* __restrict__ kvt, int split)
{
    const int idx = blockIdx.x * 256 + threadIdx.x;
    if (idx >= NH * KVSZ) return;
    const int nh  = idx / KVSZ;
    const int rem = idx - nh * KVSZ;
    const float* p = partials + (size_t)nh * split * KVSZ + rem;
    float s = 0.f;
    for (int c = 0; c < split; ++c) s += p[(size_t)c * KVSZ];
    kvt[idx] = s;
}

// ---------------------------------------------------------------------------
// Phase 2 (v5): register-tiled GEMM, Out[4096][65] = Qf[4096][64]*KV[64][65].
//  Per wave 64 rows x 32 cols, lane owns 8x4 tile; per k-chunk(4): 13
//  ds_read_b128 feed 160 FMAs; KV reused 8x, Q 4x in registers. Denominator
//  = KV row 64, accumulated per-lane for its own rows. Direct global stores.
//  (Round-6 measured ~20us ~= its 21us HBM floor -> unchanged.)
// ---------------------------------------------------------------------------
__global__ __launch_bounds__(256, 2)
void la_phase2(const float* __restrict__ Qin, const float* __restrict__ kvt,
               float* __restrict__ Out)
{
    __shared__ float sQ[128 * 68];   // 34.8 KB, row-major, stride 68
    __shared__ float sKV[KVSZ];      // 17.3 KB, [65][68] d-major

    const int b   = blockIdx.x;
    const int nh  = b >> 5;          // 32 l-chunks of 128 rows per (n,h)
    const int lc  = b & 31;
    const int n   = nh >> 3;
    const int h   = nh & 7;
    const int tid = threadIdx.x;
    const int w    = tid >> 6;
    const int lane = tid & 63;

    const float* Qc = Qin + (((size_t)n * L_L + (size_t)lc * 128) * H_H + h) * D_D;
    float*       Oc = Out + (((size_t)n * L_L + (size_t)lc * 128) * H_H + h) * D_D;

    // ---- stage KV_aug[65][68] into LDS (1105 float4, coalesced) ----
    {
        const float4* src = (const float4*)(kvt + (size_t)nh * KVSZ);
        float4*       dst = (float4*)sKV;
        #pragma unroll
        for (int it = 0; it < 4; ++it)
            dst[it * 256 + tid] = src[it * 256 + tid];
        if (tid < 81) dst[1024 + tid] = src[1024 + tid];
    }

    // ---- stage Q tile 128 rows x 64 cols (elu applied), stride 68 ----
    #pragma unroll
    for (int it = 0; it < 8; ++it) {
        const int slot = it * 256 + tid;   // 0..2047
        const int r    = slot >> 4;        // 0..127
        const int c4   = slot & 15;
        float4 v = *(const float4*)(Qc + (size_t)r * (H_H * D_D) + c4 * 4);
        v.x = elu1(v.x); v.y = elu1(v.y); v.z = elu1(v.z); v.w = elu1(v.w);
        *(float4*)&sQ[r * 68 + c4 * 4] = v;
    }
    __syncthreads();

    // ---- wave work assignment ----
    const int rt   = (w >> 1) * 64;        // row tile: 0 or 64
    const int wc   = w & 1;                // col half: 0 or 1
    const int rl   = lane & 7;             // row lane: rows rt + rl + 8j
    const int cg   = lane >> 3;            // col group
    const int ccol = wc * 32 + cg * 4;     // this lane's 4 output cols

    float acc[8][4];
    float den[8];
    #pragma unroll
    for (int j = 0; j < 8; ++j) {
        den[j] = 0.f;
        #pragma unroll
        for (int m = 0; m < 4; ++m) acc[j][m] = 0.f;
    }

    const int qbase = rt + rl;             // + 8j, stride-68 rows

    for (int kc = 0; kc < 16; ++kc) {
        // Q fragments: 8 rows x 4 k  (conflict-free b128: banks partition)
        float4 qv[8];
        #pragma unroll
        for (int j = 0; j < 8; ++j)
            qv[j] = *(const float4*)&sQ[(qbase + 8 * j) * 68 + kc * 4];
        // KV fragments: 4 k-rows x lane's 4 cols (conflict-free)
        const float4 kv0 = *(const float4*)&sKV[(kc * 4 + 0) * KVLD + ccol];
        const float4 kv1 = *(const float4*)&sKV[(kc * 4 + 1) * KVLD + ccol];
        const float4 kv2 = *(const float4*)&sKV[(kc * 4 + 2) * KVLD + ccol];
        const float4 kv3 = *(const float4*)&sKV[(kc * 4 + 3) * KVLD + ccol];
        // K_sum fragment: wave-uniform broadcast
        const float4 ks  = *(const float4*)&sKV[64 * KVLD + kc * 4];

        #pragma unroll
        for (int j = 0; j < 8; ++j) {
            const float q0 = qv[j].x, q1 = qv[j].y, q2 = qv[j].z, q3 = qv[j].w;
            den[j] = fmaf(q0, ks.x, den[j]);
            den[j] = fmaf(q1, ks.y, den[j]);
            den[j] = fmaf(q2, ks.z, den[j]);
            den[j] = fmaf(q3, ks.w, den[j]);
            acc[j][0] = fmaf(q0, kv0.x, acc[j][0]);
            acc[j][0] = fmaf(q1, kv1.x, acc[j][0]);
            acc[j][0] = fmaf(q2, kv2.x, acc[j][0]);
            acc[j][0] = fmaf(q3, kv3.x, acc[j][0]);
            acc[j][1] = fmaf(q0, kv0.y, acc[j][1]);
            acc[j][1] = fmaf(q1, kv1.y, acc[j][1]);
            acc[j][1] = fmaf(q2, kv2.y, acc[j][1]);
            acc[j][1] = fmaf(q3, kv3.y, acc[j][1]);
            acc[j][2] = fmaf(q0, kv0.z, acc[j][2]);
            acc[j][2] = fmaf(q1, kv1.z, acc[j][2]);
            acc[j][2] = fmaf(q2, kv2.z, acc[j][2]);
            acc[j][2] = fmaf(q3, kv3.z, acc[j][2]);
            acc[j][3] = fmaf(q0, kv0.w, acc[j][3]);
            acc[j][3] = fmaf(q1, kv1.w, acc[j][3]);
            acc[j][3] = fmaf(q2, kv2.w, acc[j][3]);
            acc[j][3] = fmaf(q3, kv3.w, acc[j][3]);
        }
    }

    // ---- epilogue: scale by 1/(den+eps), direct coalesced global stores ----
    #pragma unroll
    for (int j = 0; j < 8; ++j) {
        const float rz = 1.0f / (den[j] + 1e-6f);
        *(float4*)(Oc + (size_t)(qbase + 8 * j) * (H_H * D_D) + ccol) =
            make_float4(acc[j][0] * rz, acc[j][1] * rz,
                        acc[j][2] * rz, acc[j][3] * rz);
    }
}

// ---------------------------------------------------------------------------
extern "C" void kernel_launch(void* const* d_in, const int* in_sizes, int n_in,
                              void* d_out, int out_size, void* d_ws, size_t ws_size,
                              hipStream_t stream)
{
    const float* Q = (const float*)d_in[0];
    const float* K = (const float*)d_in[1];
    const float* V = (const float*)d_in[2];
    float* out = (float*)d_out;

    // ws layout: [ kvt: NH*KVSZ floats ][ partials: NH*split*KVSZ floats ]
    float* kvt = (float*)d_ws;
    const size_t kvt_bytes = (size_t)NH * KVSZ * sizeof(float);

    int split = 16;   // schunk = 256 (stage-once chunk size); 1024 blocks
    while (split > 1 &&
           kvt_bytes + (size_t)NH * split * KVSZ * sizeof(float) > ws_size)
        split >>= 1;
    float* partials = kvt + (size_t)NH * KVSZ;
    const int schunk = S_S / split;

    la_phase1<<<NH * split, 256, 0, stream>>>(K, V, partials, split, schunk);

    const int red_blocks = (NH * KVSZ + 255) / 256;   // 1105 exactly
    la_reduce<<<red_blocks, 256, 0, stream>>>(partials, kvt, split);

    la_phase2<<<NH * (L_L / 128), 256, 0, stream>>>(Q, kvt, out);
}

// Round 23
// 84.636 us; speedup vs baseline: 1.1062x; 1.1062x over previous
//
#include <hip/hip_runtime.h>
#include <hip/hip_bf16.h>
#include <cstddef>
#include <cstdint>

// Problem constants (fixed by the reference setup)
#define N_B   8
#define L_L   4096
#define S_S   4096
#define H_H   8
#define D_D   64
#define NH    64          // N_B * H_H
// KV_aug layout (d-major): rows 0..63 = KV[d][v] (stride 68, cols 64..67 pad),
// row 64 = K_sum[d] (indexed by d in cols 0..63). KVSZ floats per (n,h).
#define KVLD  68
#define KVSZ  (65 * KVLD)   // 4420
#define ROWF  (H_H * D_D)   // 512 floats per s-row
#define LDSH  260           // shorts per d-row (520B: 2-bank shift/d -> <=2-way)

typedef float f32x4 __attribute__((ext_vector_type(4)));
typedef short bf16x8 __attribute__((ext_vector_type(8)));
typedef unsigned int uint32x4 __attribute__((ext_vector_type(4)));

__device__ __forceinline__ float elu1(float x) {
    // elu(x)+1 : x>0 ? x+1 : exp(x)
    return x > 0.f ? x + 1.f : __expf(x);
}

__device__ __forceinline__ unsigned int pkbf(float a, float b) {
    __hip_bfloat162 t = __float22bfloat162_rn(make_float2(a, b));
    return *reinterpret_cast<unsigned int*>(&t);
}

// ---------------------------------------------------------------------------
// Phase 1 (v18): stage-once bf16 MFMA with FORCED 32-deep load MLP.
//  v17 post-mortem: VGPR=88 proves the compiler serialized staging into
//  load->wait->convert sub-rounds (source interleaved loads with LDS stores)
//  -> ~4-8 latencies per stage = the v14-v17-invariant ~60us. Also the
//  granule swizzle was void (d-row stride 512B == 0 mod 128B bank period;
//  d == i mod 4 within a store) -> 8-way conflicts (7.6M).
//  v18: (a) ALL 32 float4 loaded into regs first (fully-unrolled kj/vj,
//  compile-time indices), sched_barrier, then convert+write: one latency +
//  drain per stage. (b) LDSH 256->260 shorts: bank-start gains 2d term ->
//  <=2-way (free) on both packed stores and fragment reads.
//  Rest identical to the passing v17: one barrier, 8 ksteps x 5 MFMA/wave
//  (d-slab split, m89 C-layout, ones-column ksum), union'd acc epilogue.
//  LDS 2x66.6KB=133KB -> 2 blocks/CU; VGPR ~190 -> 2 waves/SIMD (8 waves).
// ---------------------------------------------------------------------------
__global__ __launch_bounds__(256, 2)
void la_phase1(const float* __restrict__ Kin, const float* __restrict__ Vin,
               float* __restrict__ partials, int split, int schunk)
{
    __shared__ union {
        struct { short Kt[64 * LDSH]; short Vt[64 * LDSH]; } st;  // 133 KB
        float acc[64 * 68];                                       // 17.4 KB
    } sm;

    const int b     = blockIdx.x;
    const int nh    = b / split;
    const int chunk = b - nh * split;
    const int n     = nh >> 3;
    const int h     = nh & 7;
    const int s0    = chunk * schunk;   // schunk == 256

    const int tid  = threadIdx.x;
    const int w    = tid >> 6;
    const int lane = tid & 63;
    const int a2   = lane & 15;        // MFMA fragment lane index
    const int kg   = lane >> 4;        // k-group (0..3)

    const size_t base = (size_t)n * S_S * ROWF + h * D_D;

    // ---- stage: issue ALL 32 loads first (full MLP), then convert+write ----
    f32x4 kj[2][8], vj[2][8];
    #pragma unroll
    for (int outer = 0; outer < 2; ++outer) {
        const int slot = outer * 256 + tid;
        const int rg   = slot >> 4;          // 0..31 (s-block of 8 rows)
        const int c4i  = slot & 15;          // 16B column group
        const float* kp = Kin + base + (size_t)(s0 + rg * 8) * ROWF + c4i * 4;
        const float* vp = Vin + base + (size_t)(s0 + rg * 8) * ROWF + c4i * 4;
        #pragma unroll
        for (int j = 0; j < 8; ++j) kj[outer][j] = *(const f32x4*)(kp + (size_t)j * ROWF);
        #pragma unroll
        for (int j = 0; j < 8; ++j) vj[outer][j] = *(const f32x4*)(vp + (size_t)j * ROWF);
    }
    __builtin_amdgcn_sched_barrier(0);   // pin: all loads issued | convert

    #pragma unroll
    for (int outer = 0; outer < 2; ++outer) {
        const int slot = outer * 256 + tid;
        const int rg   = slot >> 4;
        const int c4i  = slot & 15;
        #pragma unroll
        for (int i = 0; i < 4; ++i) {
            const int d    = c4i * 4 + i;
            const int gblk = rg ^ (d & 7);   // granule XOR swizzle
            uint32x4 pk, pv;
            pk.x = pkbf(elu1(kj[outer][0][i]), elu1(kj[outer][1][i]));
            pk.y = pkbf(elu1(kj[outer][2][i]), elu1(kj[outer][3][i]));
            pk.z = pkbf(elu1(kj[outer][4][i]), elu1(kj[outer][5][i]));
            pk.w = pkbf(elu1(kj[outer][6][i]), elu1(kj[outer][7][i]));
            pv.x = pkbf(vj[outer][0][i], vj[outer][1][i]);
            pv.y = pkbf(vj[outer][2][i], vj[outer][3][i]);
            pv.z = pkbf(vj[outer][4][i], vj[outer][5][i]);
            pv.w = pkbf(vj[outer][6][i], vj[outer][7][i]);
            *(uint32x4*)&sm.st.Kt[d * LDSH + (gblk << 3)] = pk;
            *(uint32x4*)&sm.st.Vt[d * LDSH + (gblk << 3)] = pv;
        }
    }
    __syncthreads();

    // ---- compute: wave w owns d-slab w*16..w*16+15; 8 ksteps x 5 MFMA ----
    f32x4 acc[4];
    f32x4 acck;
    const f32x4 z4 = {0.f, 0.f, 0.f, 0.f};
    acck = z4;
    #pragma unroll
    for (int nn = 0; nn < 4; ++nn) acc[nn] = z4;
    const bf16x8 ones = {0x3F80, 0x3F80, 0x3F80, 0x3F80,
                         0x3F80, 0x3F80, 0x3F80, 0x3F80};   // bf16 1.0 x8

    const int swz = a2 & 7;   // d&7 for all rows nn*16+a2 and w*16+a2
    #pragma unroll
    for (int ks = 0; ks < 8; ++ks) {
        const int goff = ((((ks << 2) | kg) ^ swz) << 3);   // swizzled granule
        const bf16x8 af = *(const bf16x8*)&sm.st.Kt[(w * 16 + a2) * LDSH + goff];
        const bf16x8 b0 = *(const bf16x8*)&sm.st.Vt[( 0 + a2) * LDSH + goff];
        const bf16x8 b1 = *(const bf16x8*)&sm.st.Vt[(16 + a2) * LDSH + goff];
        const bf16x8 b2 = *(const bf16x8*)&sm.st.Vt[(32 + a2) * LDSH + goff];
        const bf16x8 b3 = *(const bf16x8*)&sm.st.Vt[(48 + a2) * LDSH + goff];
        acc[0] = __builtin_amdgcn_mfma_f32_16x16x32_bf16(af, b0, acc[0], 0, 0, 0);
        acc[1] = __builtin_amdgcn_mfma_f32_16x16x32_bf16(af, b1, acc[1], 0, 0, 0);
        acc[2] = __builtin_amdgcn_mfma_f32_16x16x32_bf16(af, b2, acc[2], 0, 0, 0);
        acc[3] = __builtin_amdgcn_mfma_f32_16x16x32_bf16(af, b3, acc[3], 0, 0, 0);
        acck   = __builtin_amdgcn_mfma_f32_16x16x32_bf16(af, ones, acck, 0, 0, 0);
    }
    __syncthreads();   // all waves done reading Kt/Vt; acc (union) safe

    // ---- epilogue: slabs disjoint -> direct writes into sm.acc ----
    // C layout (m89): col = a2 -> v = nn*16+a2; row = kg*4+r -> d = w*16+kg*4+r
    #pragma unroll
    for (int nn = 0; nn < 4; ++nn)
        #pragma unroll
        for (int r = 0; r < 4; ++r)
            sm.acc[(w * 16 + kg * 4 + r) * 68 + nn * 16 + a2] = acc[nn][r];
    if (a2 == 0) {
        #pragma unroll
        for (int r = 0; r < 4; ++r)
            sm.acc[(w * 16 + kg * 4 + r) * 68 + 64] = acck[r];
    }
    __syncthreads();

    // write this block's partial KV_aug[65][68] d-major (row 64 = K_sum, pads 0)
    float* outp = partials + (size_t)b * KVSZ;
    for (int idx = tid; idx < KVSZ; idx += 256) {
        const int r = idx / KVLD;
        const int c = idx - r * KVLD;
        float val = 0.f;
        if (c < 64) {
            if (r < 64)
                val = sm.acc[idx];          // [d][v] stride 68 == same layout
            else
                val = sm.acc[c * 68 + 64];  // ksum for d=c (pad col 64)
        }
        outp[idx] = val;
    }
}

// ---------------------------------------------------------------------------
// Reduce: sum the `split` partials per (n,h) -> kvt[nh][65][68]
// ---------------------------------------------------------------------------
__global__ __launch_bounds__(256)
void la_reduce(const float* __restrict__ partials, float* __restrict__ kvt, int split)
{
    const int idx = blockIdx.x * 256 + threadIdx.x;
    if (idx >= NH * KVSZ) return;
    const int nh  = idx / KVSZ;
    const int rem = idx - nh * KVSZ;
    const float* p = partials + (size_t)nh * split * KVSZ + rem;
    float s = 0.f;
    for (int c = 0; c < split; ++c) s += p[(size_t)c * KVSZ];
    kvt[idx] = s;
}

// ---------------------------------------------------------------------------
// Phase 2 (v5): register-tiled GEMM, Out[4096][65] = Qf[4096][64]*KV[64][65].
//  Per wave 64 rows x 32 cols, lane owns 8x4 tile; per k-chunk(4): 13
//  ds_read_b128 feed 160 FMAs; KV reused 8x, Q 4x in registers. Denominator
//  = KV row 64, accumulated per-lane for its own rows. Direct global stores.
//  (Round-6 measured ~20us ~= its 21us HBM floor -> unchanged.)
// ---------------------------------------------------------------------------
__global__ __launch_bounds__(256, 2)
void la_phase2(const float* __restrict__ Qin, const float* __restrict__ kvt,
               float* __restrict__ Out)
{
    __shared__ float sQ[128 * 68];   // 34.8 KB, row-major, stride 68
    __shared__ float sKV[KVSZ];      // 17.3 KB, [65][68] d-major

    const int b   = blockIdx.x;
    const int nh  = b >> 5;          // 32 l-chunks of 128 rows per (n,h)
    const int lc  = b & 31;
    const int n   = nh >> 3;
    const int h   = nh & 7;
    const int tid = threadIdx.x;
    const int w    = tid >> 6;
    const int lane = tid & 63;

    const float* Qc = Qin + (((size_t)n * L_L + (size_t)lc * 128) * H_H + h) * D_D;
    float*       Oc = Out + (((size_t)n * L_L + (size_t)lc * 128) * H_H + h) * D_D;

    // ---- stage KV_aug[65][68] into LDS (1105 float4, coalesced) ----
    {
        const float4* src = (const float4*)(kvt + (size_t)nh * KVSZ);
        float4*       dst = (float4*)sKV;
        #pragma unroll
        for (int it = 0; it < 4; ++it)
            dst[it * 256 + tid] = src[it * 256 + tid];
        if (tid < 81) dst[1024 + tid] = src[1024 + tid];
    }

    // ---- stage Q tile 128 rows x 64 cols (elu applied), stride 68 ----
    #pragma unroll
    for (int it = 0; it < 8; ++it) {
        const int slot = it * 256 + tid;   // 0..2047
        const int r    = slot >> 4;        // 0..127
        const int c4   = slot & 15;
        float4 v = *(const float4*)(Qc + (size_t)r * (H_H * D_D) + c4 * 4);
        v.x = elu1(v.x); v.y = elu1(v.y); v.z = elu1(v.z); v.w = elu1(v.w);
        *(float4*)&sQ[r * 68 + c4 * 4] = v;
    }
    __syncthreads();

    // ---- wave work assignment ----
    const int rt   = (w >> 1) * 64;        // row tile: 0 or 64
    const int wc   = w & 1;                // col half: 0 or 1
    const int rl   = lane & 7;             // row lane: rows rt + rl + 8j
    const int cg   = lane >> 3;            // col group
    const int ccol = wc * 32 + cg * 4;     // this lane's 4 output cols

    float acc[8][4];
    float den[8];
    #pragma unroll
    for (int j = 0; j < 8; ++j) {
        den[j] = 0.f;
        #pragma unroll
        for (int m = 0; m < 4; ++m) acc[j][m] = 0.f;
    }

    const int qbase = rt + rl;             // + 8j, stride-68 rows

    for (int kc = 0; kc < 16; ++kc) {
        // Q fragments: 8 rows x 4 k  (conflict-free b128: banks partition)
        float4 qv[8];
        #pragma unroll
        for (int j = 0; j < 8; ++j)
            qv[j] = *(const float4*)&sQ[(qbase + 8 * j) * 68 + kc * 4];
        // KV fragments: 4 k-rows x lane's 4 cols (conflict-free)
        const float4 kv0 = *(const float4*)&sKV[(kc * 4 + 0) * KVLD + ccol];
        const float4 kv1 = *(const float4*)&sKV[(kc * 4 + 1) * KVLD + ccol];
        const float4 kv2 = *(const float4*)&sKV[(kc * 4 + 2) * KVLD + ccol];
        const float4 kv3 = *(const float4*)&sKV[(kc * 4 + 3) * KVLD + ccol];
        // K_sum fragment: wave-uniform broadcast
        const float4 ks  = *(const float4*)&sKV[64 * KVLD + kc * 4];

        #pragma unroll
        for (int j = 0; j < 8; ++j) {
            const float q0 = qv[j].x, q1 = qv[j].y, q2 = qv[j].z, q3 = qv[j].w;
            den[j] = fmaf(q0, ks.x, den[j]);
            den[j] = fmaf(q1, ks.y, den[j]);
            den[j] = fmaf(q2, ks.z, den[j]);
            den[j] = fmaf(q3, ks.w, den[j]);
            acc[j][0] = fmaf(q0, kv0.x, acc[j][0]);
            acc[j][0] = fmaf(q1, kv1.x, acc[j][0]);
            acc[j][0] = fmaf(q2, kv2.x, acc[j][0]);
            acc[j][0] = fmaf(q3, kv3.x, acc[j][0]);
            acc[j][1] = fmaf(q0, kv0.y, acc[j][1]);
            acc[j][1] = fmaf(q1, kv1.y, acc[j][1]);
            acc[j][1] = fmaf(q2, kv2.y, acc[j][1]);
            acc[j][1] = fmaf(q3, kv3.y, acc[j][1]);
            acc[j][2] = fmaf(q0, kv0.z, acc[j][2]);
            acc[j][2] = fmaf(q1, kv1.z, acc[j][2]);
            acc[j][2] = fmaf(q2, kv2.z, acc[j][2]);
            acc[j][2] = fmaf(q3, kv3.z, acc[j][2]);
            acc[j][3] = fmaf(q0, kv0.w, acc[j][3]);
            acc[j][3] = fmaf(q1, kv1.w, acc[j][3]);
            acc[j][3] = fmaf(q2, kv2.w, acc[j][3]);
            acc[j][3] = fmaf(q3, kv3.w, acc[j][3]);
        }
    }

    // ---- epilogue: scale by 1/(den+eps), direct coalesced global stores ----
    #pragma unroll
    for (int j = 0; j < 8; ++j) {
        const float rz = 1.0f / (den[j] + 1e-6f);
        *(float4*)(Oc + (size_t)(qbase + 8 * j) * (H_H * D_D) + ccol) =
            make_float4(acc[j][0] * rz, acc[j][1] * rz,
                        acc[j][2] * rz, acc[j][3] * rz);
    }
}

// ---------------------------------------------------------------------------
extern "C" void kernel_launch(void* const* d_in, const int* in_sizes, int n_in,
                              void* d_out, int out_size, void* d_ws, size_t ws_size,
                              hipStream_t stream)
{
    const float* Q = (const float*)d_in[0];
    const float* K = (const float*)d_in[1];
    const float* V = (const float*)d_in[2];
    float* out = (float*)d_out;

    // ws layout: [ kvt: NH*KVSZ floats ][ partials: NH*split*KVSZ floats ]
    float* kvt = (float*)d_ws;
    const size_t kvt_bytes = (size_t)NH * KVSZ * sizeof(float);

    int split = 16;   // schunk = 256 (stage-once chunk size); 1024 blocks
    while (split > 1 &&
           kvt_bytes + (size_t)NH * split * KVSZ * sizeof(float) > ws_size)
        split >>= 1;
    float* partials = kvt + (size_t)NH * KVSZ;
    const int schunk = S_S / split;

    la_phase1<<<NH * split, 256, 0, stream>>>(K, V, partials, split, schunk);

    const int red_blocks = (NH * KVSZ + 255) / 256;   // 1105 exactly
    la_reduce<<<red_blocks, 256, 0, stream>>>(partials, kvt, split);

    la_phase2<<<NH * (L_L / 128), 256, 0, stream>>>(Q, kvt, out);
}